// Round 4
// baseline (87.627 us; speedup 1.0000x reference)
//
#include <hip/hip_runtime.h>
#include <cstddef>
#include <cstdint>

// B=256, S=16384, R=16, N=6.
//   V_k[b,(d,e)] = sum_s z[b,s]*core_k[d,s,e]  (k=1..5) -> bf16-split MFMA GEMM
//   W[b] = V1..V5 chain; out[b,s] = sum_d c0[s,d]*W[b,d]
//
// R4 design: LDS-FREE GEMM. Both MFMA fragments load straight from global:
//   A (z):    lane(row=l&15, k=(l>>4)*8+j) -> 8 consecutive floats = 2 dwordx4
//   B (core): lane(col=e=l&15, k=(l>>4)*8+j) -> 8 dwords stride 16 floats
//             (each instr = 4 dense 64B lines; 4 waves/block share via L1/L2)
// cvt f32 -> bf16 hi/lo in registers. LDS pipe (per-CU, ~100B/cyc) was the
// R2/R3 bottleneck; MFMA pipes are per-SIMD. No barriers at all.
namespace {
constexpr int kB = 256;
constexpr int kS = 16384;
constexpr int kNCol = 1040;   // 4 cores * 256 + 16 (core5)
}

using short8 = __attribute__((ext_vector_type(8))) short;   // 8 bf16
using f32x4  = __attribute__((ext_vector_type(4))) float;

// truncation split: x ~= hi + lo (bf16 each)
__device__ __forceinline__ void cvt8r(const float* __restrict__ x,
                                      short8& h, short8& l) {
    #pragma unroll
    for (int i = 0; i < 8; ++i) {
        uint32_t u = __float_as_uint(x[i]);
        h[i] = (short)(u >> 16);
        float r = x[i] - __uint_as_float(u & 0xffff0000u);
        l[i] = (short)(__float_as_uint(r) >> 16);
    }
}

// ---------------------------------------------------------------------------
// GEMM: vp[sk][b][col] partial of z @ G over k-chunk sk.
// grid = 17*splitk (sk-major flat, XCD-swizzled); block = 4 waves.
// wave w -> rows w*64..+63; block covers cols cg*64..+63 (cg==16: core5, 16).
// Per wave: tile 64x64, fm=fn=4, 16x16x32 bf16 MFMA, 3-term split
// (hi*hi + hi*lo + lo*hi). Register-prefetch next 32-k slab under MFMA.
// ---------------------------------------------------------------------------
__global__ __launch_bounds__(256, 2) void fttv_gemm_reg(
    const float* __restrict__ z,
    const float* __restrict__ c1, const float* __restrict__ c2,
    const float* __restrict__ c3, const float* __restrict__ c4,
    const float* __restrict__ c5,
    float* __restrict__ vp, int kc)
{
    // bijective XCD swizzle; flat = sk*17+cg so one XCD owns whole sk-chunks
    const int nwg = gridDim.x;
    const int q = nwg >> 3, r = nwg & 7;
    const int xcd = blockIdx.x & 7, rest = blockIdx.x >> 3;
    const int vfl = (xcd < r ? xcd * (q + 1) : r * (q + 1) + (xcd - r) * q) + rest;
    const int sk = vfl / 17;
    const int cg = vfl - sk * 17;

    const int tid = threadIdx.x, w = tid >> 6, l = tid & 63;
    const int lr = l & 15;         // frag row/col lane index
    const int lk = (l >> 4) * 8;   // frag k sub-offset
    const int row0 = w * 64;
    const int kbeg = sk * kc;

    // A lane pointers per fm (8 consecutive floats each slab)
    const float* za[4];
    #pragma unroll
    for (int fm = 0; fm < 4; ++fm)
        za[fm] = z + (size_t)(row0 + fm * 16 + lr) * kS + kbeg + lk;

    f32x4 acc[4][4];
    #pragma unroll
    for (int i = 0; i < 4; ++i)
        #pragma unroll
        for (int j = 0; j < 4; ++j) acc[i][j] = (f32x4){0.f, 0.f, 0.f, 0.f};

    float ra[4][8];

    if (cg < 16) {
        const int ci = cg >> 2;
        const float* cp = (ci == 0 ? c1 : ci == 1 ? c2 : ci == 2 ? c3 : c4);
        const int d0 = (cg & 3) * 4;
        // B lane pointers per fn: core[d0+fn][k][e=lr], k-stride 16 floats
        const float* bpt[4];
        #pragma unroll
        for (int fn = 0; fn < 4; ++fn)
            bpt[fn] = cp + (size_t)(d0 + fn) * kS * 16
                    + (size_t)(kbeg + lk) * 16 + lr;

        float rb[4][8];
        // prologue loads (slab 0)
        #pragma unroll
        for (int fm = 0; fm < 4; ++fm) {
            *reinterpret_cast<float4*>(&ra[fm][0]) =
                *reinterpret_cast<const float4*>(za[fm]);
            *reinterpret_cast<float4*>(&ra[fm][4]) =
                *reinterpret_cast<const float4*>(za[fm] + 4);
        }
        #pragma unroll
        for (int fn = 0; fn < 4; ++fn)
            #pragma unroll
            for (int j = 0; j < 8; ++j)
                rb[fn][j] = bpt[fn][(size_t)j * 16];

        for (int kk = 0; kk < kc; kk += 32) {
            short8 ah[4], al[4], bh[4], bl[4];
            #pragma unroll
            for (int fm = 0; fm < 4; ++fm) cvt8r(ra[fm], ah[fm], al[fm]);
            #pragma unroll
            for (int fn = 0; fn < 4; ++fn) cvt8r(rb[fn], bh[fn], bl[fn]);
            if (kk + 32 < kc) {   // prefetch next slab (lands under MFMA)
                #pragma unroll
                for (int fm = 0; fm < 4; ++fm) {
                    *reinterpret_cast<float4*>(&ra[fm][0]) =
                        *reinterpret_cast<const float4*>(za[fm] + kk + 32);
                    *reinterpret_cast<float4*>(&ra[fm][4]) =
                        *reinterpret_cast<const float4*>(za[fm] + kk + 36);
                }
                #pragma unroll
                for (int fn = 0; fn < 4; ++fn)
                    #pragma unroll
                    for (int j = 0; j < 8; ++j)
                        rb[fn][j] = bpt[fn][(size_t)(kk + 32 + j) * 16];
            }
            #pragma unroll
            for (int fm = 0; fm < 4; ++fm)
                #pragma unroll
                for (int fn = 0; fn < 4; ++fn) {
                    acc[fm][fn] = __builtin_amdgcn_mfma_f32_16x16x32_bf16(
                        ah[fm], bh[fn], acc[fm][fn], 0, 0, 0);
                    acc[fm][fn] = __builtin_amdgcn_mfma_f32_16x16x32_bf16(
                        ah[fm], bl[fn], acc[fm][fn], 0, 0, 0);
                    acc[fm][fn] = __builtin_amdgcn_mfma_f32_16x16x32_bf16(
                        al[fm], bh[fn], acc[fm][fn], 0, 0, 0);
                }
        }
        // epilogue: C frag (col=l&15, row=(l>>4)*4+qq); 64B-coalesced dwords
        #pragma unroll
        for (int fm = 0; fm < 4; ++fm)
            #pragma unroll
            for (int fn = 0; fn < 4; ++fn) {
                const int col = cg * 64 + fn * 16 + lr;
                const int brow = row0 + fm * 16 + (l >> 4) * 4;
                #pragma unroll
                for (int qq = 0; qq < 4; ++qq)
                    vp[((size_t)sk * kB + brow + qq) * kNCol + col] =
                        acc[fm][fn][qq];
            }
    } else {
        // core5 runt: 16 cols; B lane loads are 8 CONSECUTIVE floats
        const float* bpt5 = c5 + (size_t)lr * kS + kbeg + lk;
        float rb[8];
        #pragma unroll
        for (int fm = 0; fm < 4; ++fm) {
            *reinterpret_cast<float4*>(&ra[fm][0]) =
                *reinterpret_cast<const float4*>(za[fm]);
            *reinterpret_cast<float4*>(&ra[fm][4]) =
                *reinterpret_cast<const float4*>(za[fm] + 4);
        }
        *reinterpret_cast<float4*>(&rb[0]) =
            *reinterpret_cast<const float4*>(bpt5);
        *reinterpret_cast<float4*>(&rb[4]) =
            *reinterpret_cast<const float4*>(bpt5 + 4);

        for (int kk = 0; kk < kc; kk += 32) {
            short8 ah[4], al[4], bh, bl;
            #pragma unroll
            for (int fm = 0; fm < 4; ++fm) cvt8r(ra[fm], ah[fm], al[fm]);
            cvt8r(rb, bh, bl);
            if (kk + 32 < kc) {
                #pragma unroll
                for (int fm = 0; fm < 4; ++fm) {
                    *reinterpret_cast<float4*>(&ra[fm][0]) =
                        *reinterpret_cast<const float4*>(za[fm] + kk + 32);
                    *reinterpret_cast<float4*>(&ra[fm][4]) =
                        *reinterpret_cast<const float4*>(za[fm] + kk + 36);
                }
                *reinterpret_cast<float4*>(&rb[0]) =
                    *reinterpret_cast<const float4*>(bpt5 + kk + 32);
                *reinterpret_cast<float4*>(&rb[4]) =
                    *reinterpret_cast<const float4*>(bpt5 + kk + 36);
            }
            #pragma unroll
            for (int fm = 0; fm < 4; ++fm) {
                acc[fm][0] = __builtin_amdgcn_mfma_f32_16x16x32_bf16(
                    ah[fm], bh, acc[fm][0], 0, 0, 0);
                acc[fm][0] = __builtin_amdgcn_mfma_f32_16x16x32_bf16(
                    ah[fm], bl, acc[fm][0], 0, 0, 0);
                acc[fm][0] = __builtin_amdgcn_mfma_f32_16x16x32_bf16(
                    al[fm], bh, acc[fm][0], 0, 0, 0);
            }
        }
        #pragma unroll
        for (int fm = 0; fm < 4; ++fm) {
            const int col = 1024 + lr;
            const int brow = row0 + fm * 16 + (l >> 4) * 4;
            #pragma unroll
            for (int qq = 0; qq < 4; ++qq)
                vp[((size_t)sk * kB + brow + qq) * kNCol + col] = acc[fm][0][qq];
        }
    }
}

// ---------------------------------------------------------------------------
// v[b][col] = sum_sk vp[sk][b][col]; float4, fully coalesced.
// grid = 260 blocks x 256 thr (covers 1040*256/4 float4s)
__global__ void fttv_reduce(const float* __restrict__ vp, float* __restrict__ v,
                            int splitk)
{
    const int i4 = blockIdx.x * 256 + threadIdx.x;
    float4 s = make_float4(0.f, 0.f, 0.f, 0.f);
    for (int k = 0; k < splitk; ++k) {
        const float4 t = *reinterpret_cast<const float4*>(
            vp + (size_t)k * kNCol * kB + (size_t)i4 * 4);
        s.x += t.x; s.y += t.y; s.z += t.z; s.w += t.w;
    }
    *reinterpret_cast<float4*>(v + (size_t)i4 * 4) = s;
}

// W[b] = V1@V2@V3@V4@V5col; one 64-thr block per batch; v layout [b][col]
__global__ void fttv_chain(const float* __restrict__ v, float* __restrict__ w)
{
    const int b = blockIdx.x;
    const float* vb = v + (size_t)b * kNCol;
    const int lane = threadIdx.x;
    const int d = lane & 15;
    float u = vb[1024 + d];
    #pragma unroll
    for (int k = 4; k >= 1; --k) {
        float nu = 0.f;
        #pragma unroll
        for (int e = 0; e < 16; ++e) {
            const float ue = __shfl(u, e, 16);
            nu += vb[(k - 1) * 256 + d * 16 + e] * ue;
        }
        u = nu;
    }
    if (lane < 16) w[b * 16 + d] = u;
}

// out[b,s] = sum_d c0[s,d] * W[b,d]
__global__ __launch_bounds__(256) void fttv_out(
    const float* __restrict__ c0, const float* __restrict__ w,
    float* __restrict__ out)
{
    __shared__ float wl[64][16];
    const int sc = blockIdx.x & 63;
    const int bq = blockIdx.x >> 6;
    const int tid = threadIdx.x;
    const int s = sc * 256 + tid;
    float f0[16];
    #pragma unroll
    for (int q = 0; q < 4; ++q)
        *reinterpret_cast<float4*>(&f0[q * 4]) =
            *reinterpret_cast<const float4*>(c0 + (size_t)s * 16 + q * 4);
    *reinterpret_cast<float4*>(&wl[0][0] + tid * 4) =
        *reinterpret_cast<const float4*>(w + bq * 1024 + tid * 4);
    __syncthreads();
    for (int bb = 0; bb < 64; ++bb) {
        float a = 0.f;
        #pragma unroll
        for (int d = 0; d < 16; ++d) a += f0[d] * wl[bb][d];
        out[(size_t)(bq * 64 + bb) * kS + s] = a;
    }
}

// ---------------------------------------------------------------------------
extern "C" void kernel_launch(void* const* d_in, const int* in_sizes, int n_in,
                              void* d_out, int out_size, void* d_ws, size_t ws_size,
                              hipStream_t stream)
{
    (void)in_sizes; (void)n_in; (void)out_size;
    const float* z  = (const float*)d_in[0];
    const float* c0 = (const float*)d_in[1];
    const float* c1 = (const float*)d_in[2];
    const float* c2 = (const float*)d_in[3];
    const float* c3 = (const float*)d_in[4];
    const float* c4 = (const float*)d_in[5];
    const float* c5 = (const float*)d_in[6];
    float* out = (float*)d_out;
    float* ws  = (float*)d_ws;

    // ws: vp[splitk][256][1040] | v[256][1040] | w[256][16]
    int splitk = 32;
    while (splitk > 1 &&
           ((size_t)(splitk + 1) * kNCol * kB + (size_t)kB * 16) * sizeof(float) > ws_size)
        splitk >>= 1;
    const int kc = kS / splitk;   // multiple of 32 for splitk <= 512

    float* vp = ws;
    float* v  = vp + (size_t)splitk * kNCol * kB;
    float* w  = v + (size_t)kNCol * kB;

    fttv_gemm_reg<<<dim3(17 * splitk), 256, 0, stream>>>(z, c1, c2, c3, c4, c5, vp, kc);
    fttv_reduce<<<dim3(kNCol * kB / 1024), 256, 0, stream>>>(vp, v, splitk);
    fttv_chain<<<dim3(kB), 64, 0, stream>>>(v, w);
    fttv_out<<<dim3(256), 256, 0, stream>>>(c0, w, out);
}